// Round 3
// baseline (206.340 us; speedup 1.0000x reference)
//
#include <hip/hip_runtime.h>

#define HH 160
#define WW 160
#define PLANE (HH*WW)

// input:  (8, 1, 9, 160, 160) f32
// weight: (3, 3, 48, 3) f32
// offset: (16, 3, 2) f32
// out:    (16, 48, 160, 160) f32
//
// out[ob, g*16+o, i, j] = sum_{k=kh*3+kw, c} sample(inp[ob/2, g*3+c],
//     i + (kh-1)*(1+3/off[ob,g,0]), j + (kw-1)*(1+3/off[ob,g,1])) * W[kh,kw,g*16+o,c]
// with zero-padded bilinear sampling.

__global__ __launch_bounds__(256) void dcn_kernel(
    const float* __restrict__ inp,
    const float* __restrict__ weight,
    const float* __restrict__ offset,
    float* __restrict__ out)
{
    __shared__ float w_lds[3 * 9 * 16];   // [c][k][o], 432 floats

    const int tid = threadIdx.x;
    const int bg  = blockIdx.y;           // ob*3 + g over 48
    const int ob  = bg / 3;
    const int g   = bg % 3;

    // Stage weight slice for this group: w_lds[(c*9 + k)*16 + o] = weight[(k*48 + g*16 + o)*3 + c]
    for (int idx = tid; idx < 3 * 9 * 16; idx += 256) {
        const int o  = idx & 15;
        const int ck = idx >> 4;
        const int k  = ck % 9;
        const int c  = ck / 9;
        w_lds[idx] = weight[(k * 48 + g * 16 + o) * 3 + c];
    }
    __syncthreads();

    const float offy = offset[bg * 2 + 0];
    const float offx = offset[bg * 2 + 1];
    const float fy = 1.0f + 3.0f / offy;
    const float fx = 1.0f + 3.0f / offx;

    const int p = blockIdx.x * 256 + tid;   // 25600 = 100 blocks * 256, exact
    const int i = p / WW;
    const int j = p - i * WW;

    int   y0i[3], x0i[3];
    float wy[3], wx[3];
#pragma unroll
    for (int t = 0; t < 3; ++t) {
        const float yy  = (float)i + (float)(t - 1) * fy;
        const float y0f = floorf(yy);
        wy[t]  = yy - y0f;
        y0i[t] = (int)y0f;
        const float xx  = (float)j + (float)(t - 1) * fx;
        const float x0f = floorf(xx);
        wx[t]  = xx - x0f;
        x0i[t] = (int)x0f;
    }

    const float* ibase = inp + ((size_t)(ob >> 1) * 9 + (size_t)g * 3) * PLANE;

    float acc[16];
#pragma unroll
    for (int o = 0; o < 16; ++o) acc[o] = 0.0f;

#pragma unroll
    for (int kh = 0; kh < 3; ++kh) {
        const int   y0   = y0i[kh];
        const float wyv  = wy[kh];
        const bool  y0ok = (unsigned)y0 < (unsigned)HH;
        const bool  y1ok = (unsigned)(y0 + 1) < (unsigned)HH;
        const int   y0c  = min(max(y0, 0), HH - 1) * WW;
        const int   y1c  = min(max(y0 + 1, 0), HH - 1) * WW;
#pragma unroll
        for (int kw = 0; kw < 3; ++kw) {
            const int   x0   = x0i[kw];
            const float wxv  = wx[kw];
            const bool  x0ok = (unsigned)x0 < (unsigned)WW;
            const bool  x1ok = (unsigned)(x0 + 1) < (unsigned)WW;
            const int   x0c  = min(max(x0, 0), WW - 1);
            const int   x1c  = min(max(x0 + 1, 0), WW - 1);
            const int   k    = kh * 3 + kw;
#pragma unroll
            for (int c = 0; c < 3; ++c) {
                const float* pc = ibase + c * PLANE;
                const float v00 = (y0ok & x0ok) ? pc[y0c + x0c] : 0.0f;
                const float v01 = (y0ok & x1ok) ? pc[y0c + x1c] : 0.0f;
                const float v10 = (y1ok & x0ok) ? pc[y1c + x0c] : 0.0f;
                const float v11 = (y1ok & x1ok) ? pc[y1c + x1c] : 0.0f;
                // y-lerp first (matches reference), then x-lerp
                const float r0 = v00 * (1.0f - wyv) + v10 * wyv;
                const float r1 = v01 * (1.0f - wyv) + v11 * wyv;
                const float s  = r0 * (1.0f - wxv) + r1 * wxv;
                const float* wp = &w_lds[(c * 9 + k) * 16];
#pragma unroll
                for (int o = 0; o < 16; ++o) acc[o] = fmaf(s, wp[o], acc[o]);
            }
        }
    }

    float* obase = out + ((size_t)ob * 48 + (size_t)g * 16) * PLANE + p;
#pragma unroll
    for (int o = 0; o < 16; ++o) obase[o * PLANE] = acc[o];
}

extern "C" void kernel_launch(void* const* d_in, const int* in_sizes, int n_in,
                              void* d_out, int out_size, void* d_ws, size_t ws_size,
                              hipStream_t stream) {
    const float* inp    = (const float*)d_in[0];
    const float* weight = (const float*)d_in[1];
    const float* offset = (const float*)d_in[2];
    float* out = (float*)d_out;

    dim3 grid(PLANE / 256, 16 * 3, 1);   // 100 x 48
    dim3 block(256, 1, 1);
    dcn_kernel<<<grid, block, 0, stream>>>(inp, weight, offset, out);
}